// Round 22
// baseline (157.760 us; speedup 1.0000x reference)
//
#include <hip/hip_runtime.h>
#include <math.h>

#define NN 100000
#define NE 1600000
#define D 128

#define NHB 1564                        // half-buckets of 64 dst-nodes
#define CAPB 1280                       // ebuf capacity per half-bucket (mean 1023, +8 sigma)
#define CURSTRIDE 16                    // cursor padded to one 64B line
#define SC_BLOCKS 782                   // scatter role blocks
#define SC_CHUNK 2048                   // edges per scatter block
#define SC_IT 8                         // 2048/256
#define CAP 1280                        // pull sorted tile (== CAPB)

#define BM 64                           // rows per gemm block
#define GM_BLOCKS 1563                  // ceil(NN/64)
#define GRID (SC_BLOCKS + GM_BLOCKS)    // 2345
#define TPAD 264                        // transpose-epilogue row stride (bytes)

#define ASG __attribute__((address_space(1)))
#define ASL __attribute__((address_space(3)))

typedef __attribute__((ext_vector_type(8))) short bf16x8;
typedef __attribute__((ext_vector_type(4))) float f32x4;
typedef __attribute__((ext_vector_type(4))) unsigned int u32x4;

__device__ __forceinline__ unsigned int cvt_pk_bf16(float lo, float hi) {
    unsigned int r;
    asm("v_cvt_pk_bf16_f32 %0, %1, %2" : "=v"(r) : "v"(lo), "v"(hi));
    return r;
}

// Pack two f32 -> packed f16 pair (round toward zero), as a dword.
__device__ __forceinline__ unsigned int cvt_pk_f16(float lo, float hi) {
    auto p = __builtin_amdgcn_cvt_pkrtz(lo, hi);
    return __builtin_bit_cast(unsigned int, p);
}

// Single-instruction f16-half * f32 + f32 (VOP3P v_fma_mix_f32, gfx9+).
__device__ __forceinline__ void fma_f16lo(float& acc, unsigned int h, float v) {
    asm("v_fma_mix_f32 %0, %1, %2, %0 op_sel:[0,0,0] op_sel_hi:[1,0,0]"
        : "+v"(acc) : "v"(h), "v"(v));
}
__device__ __forceinline__ void fma_f16hi(float& acc, unsigned int h, float v) {
    asm("v_fma_mix_f32 %0, %1, %2, %0 op_sel:[1,0,0] op_sel_hi:[1,0,0]"
        : "+v"(acc) : "v"(h), "v"(v));
}

// ---------------------------------------------------------------------------
// W precompute (fp32 -> bf16, slot-swizzled) + padded cursor zeroing.
// ---------------------------------------------------------------------------
__global__ __launch_bounds__(256) void wconv_kernel(const float* __restrict__ W,
                                                    unsigned short* __restrict__ Wswz,
                                                    int* __restrict__ bucketCursor) {
    int i = blockIdx.x * 256 + threadIdx.x;   // 2048 threads total
    int r = i >> 4, s = i & 15;
    const float4* wp = reinterpret_cast<const float4*>(W + (size_t)r * D + s * 8);
    float4 v0 = wp[0], v1 = wp[1];
    uint2 a, b;
    a.x = cvt_pk_bf16(v0.x, v0.y); a.y = cvt_pk_bf16(v0.z, v0.w);
    b.x = cvt_pk_bf16(v1.x, v1.y); b.y = cvt_pk_bf16(v1.z, v1.w);
    int so = s ^ (r & 15);
    unsigned short* op = Wswz + (size_t)r * D + so * 8;
    *reinterpret_cast<uint2*>(op)     = a;
    *reinterpret_cast<uint2*>(op + 4) = b;
    for (int z = i; z < NHB * CURSTRIDE; z += 2048) bucketCursor[z] = 0;
}

// ---------------------------------------------------------------------------
// FUSED gemm + scatter. Scatter now bins at HALF-BUCKET granularity (1564
// bins of 64 nodes) so pull owns its region outright (no filtering).
// ---------------------------------------------------------------------------
__global__ __launch_bounds__(256) void gemm_scatter_kernel(const float* __restrict__ x,
                                                           const unsigned short* __restrict__ Wswz,
                                                           unsigned short* __restrict__ h,
                                                           const int* __restrict__ src,
                                                           const int* __restrict__ dst,
                                                           const float* __restrict__ vals,
                                                           int* __restrict__ bucketCursor,
                                                           uint2* __restrict__ ebuf) {
    __shared__ __align__(16) unsigned char smem[40960];
    const int tid = threadIdx.x;
    const int lane = tid & 63;
    const int w = tid >> 6;
    const int g = blockIdx.x;

    if (g < SC_BLOCKS) {
        // ================= SCATTER role (1564 half-bucket bins) ===========
        uint2* s_rec        = reinterpret_cast<uint2*>(smem);                    // 16384 B
        unsigned short* s_b = reinterpret_cast<unsigned short*>(smem + 16384);   // 4096 B
        int*   l_off        = reinterpret_cast<int*>(smem + 20480);              // 6256 B
        int*   l_cur        = reinterpret_cast<int*>(smem + 26736);              // 6256 B
        int*   l_cnt        = reinterpret_cast<int*>(smem + 32992);              // 6256 B
        int*   wtot         = reinterpret_cast<int*>(smem + 39248);              // 16 B

        const int t = tid;
        const int cb = g * SC_CHUNK;

        for (int i = t; i < NHB; i += 256) l_cnt[i] = 0;
        __syncthreads();

        int dreg[SC_IT];
#pragma unroll
        for (int i = 0; i < SC_IT; ++i) {
            int o = t + 256 * i;
            int e = cb + o;
            dreg[i] = (e < NE) ? dst[e] : -1;
            if (dreg[i] >= 0) atomicAdd(&l_cnt[dreg[i] >> 6], 1);
        }
        __syncthreads();

        // scan of 1564 bins: 7 bins/thread, wave shfl scan + 4-wave combine
        int c[7];
        int s = 0;
#pragma unroll
        for (int i = 0; i < 7; ++i) {
            int b = 7 * t + i;
            c[i] = (b < NHB) ? l_cnt[b] : 0;
            s += c[i];
        }
        int incl = s;
#pragma unroll
        for (int off = 1; off < 64; off <<= 1) {
            int v = __shfl_up(incl, off);
            if (lane >= off) incl += v;
        }
        if (lane == 63) wtot[w] = incl;
        __syncthreads();
        int run = incl - s;
        for (int k = 0; k < 4; ++k) if (k < w) run += wtot[k];
#pragma unroll
        for (int i = 0; i < 7; ++i) {
            int b = 7 * t + i;
            if (b < NHB) {
                l_cur[b] = run;
                int gbase = b * CAPB +
                    (c[i] ? atomicAdd(&bucketCursor[b * CURSTRIDE], c[i]) : 0);
                l_off[b] = gbase - run;
            }
            run += c[i];
        }
        __syncthreads();

#pragma unroll
        for (int i = 0; i < SC_IT; ++i) {
            int o = t + 256 * i;
            if (dreg[i] >= 0) {
                int dn = dreg[i];
                int b = dn >> 6;
                uint2 rec;
                rec.x = (unsigned int)src[cb + o] | ((unsigned int)(dn & 63) << 17);
                rec.y = __float_as_uint(vals[cb + o]);
                int lofs = atomicAdd(&l_cur[b], 1);
                s_rec[lofs] = rec;
                s_b[lofs] = (unsigned short)b;
            }
        }
        __syncthreads();

        const int nloc = min(SC_CHUNK, NE - cb);
#pragma unroll
        for (int i = 0; i < SC_IT; ++i) {
            int j = t + 256 * i;
            if (j < nloc) {
                int b = s_b[j];
                ebuf[l_off[b] + j] = s_rec[j];
            }
        }
    } else {
        // ================= GEMM role (BM=64, reg-A, f16 h) =================
        unsigned char* lBbuf = smem;                                   // 32768 B
        const int rowBase = (g - SC_BLOCKS) * BM;

#pragma unroll
        for (int q = 0; q < 8; ++q) {
            const unsigned char* gp = reinterpret_cast<const unsigned char*>(Wswz)
                                      + (size_t)((w * 8 + q) * 1024 + lane * 16);
            unsigned char* lp = lBbuf + (w * 8 + q) * 1024;
            __builtin_amdgcn_global_load_lds((ASG const unsigned int*)(const void*)gp,
                                             (ASL unsigned int*)(void*)lp, 16, 0, 0);
        }

        const int l16 = lane & 15;
        const int arow = min(rowBase + w * 16 + l16, NN - 1);
        const float* xrow = x + (size_t)arow * D + (lane >> 4) * 8;

        bf16x8 afr[4];
#pragma unroll
        for (int kk = 0; kk < 4; ++kk) {
            float4 v0 = *reinterpret_cast<const float4*>(xrow + kk * 32);
            float4 v1 = *reinterpret_cast<const float4*>(xrow + kk * 32 + 4);
            u32x4 u;
            u[0] = cvt_pk_bf16(v0.x, v0.y);
            u[1] = cvt_pk_bf16(v0.z, v0.w);
            u[2] = cvt_pk_bf16(v1.x, v1.y);
            u[3] = cvt_pk_bf16(v1.z, v1.w);
            afr[kk] = __builtin_bit_cast(bf16x8, u);
        }
        __syncthreads();   // drains vmcnt (W DMA)

        const int kx16 = (lane >> 4) * 16;
        f32x4 acc[8];
#pragma unroll
        for (int j = 0; j < 8; ++j) acc[j] = (f32x4){0.f, 0.f, 0.f, 0.f};

        const int bxor = l16 << 4;
#pragma unroll
        for (int kk = 0; kk < 4; ++kk) {
            int kbyte = kk * 64 + kx16;
#pragma unroll
            for (int j = 0; j < 8; ++j) {
                int row = j * 16 + l16;
                bf16x8 b = *reinterpret_cast<const bf16x8*>(
                    lBbuf + row * 256 + (kbyte ^ bxor));
                acc[j] = __builtin_amdgcn_mfma_f32_16x16x32_bf16(afr[kk], b, acc[j], 0, 0, 0);
            }
        }
        __syncthreads();   // all waves done with lB -> reuse as transpose buffer

        const int lr0 = w * 16 + (lane >> 4) * 4;
#pragma unroll
        for (int j = 0; j < 8; ++j) {
            int col = j * 16 + l16;
            unsigned int d01 = cvt_pk_f16(acc[j][0], acc[j][1]);
            unsigned int d23 = cvt_pk_f16(acc[j][2], acc[j][3]);
            unsigned char* p0 = lBbuf + lr0 * TPAD + col * 2;
            *reinterpret_cast<unsigned short*>(p0)            = (unsigned short)d01;
            *reinterpret_cast<unsigned short*>(p0 + TPAD)     = (unsigned short)(d01 >> 16);
            *reinterpret_cast<unsigned short*>(p0 + 2 * TPAD) = (unsigned short)d23;
            *reinterpret_cast<unsigned short*>(p0 + 3 * TPAD) = (unsigned short)(d23 >> 16);
        }
        __syncthreads();

#pragma unroll
        for (int i = 0; i < 8; ++i) {
            int f = tid + 256 * i;
            int r = f >> 5, c = f & 31;
            if (rowBase + r < NN) {
                uint2 v = *reinterpret_cast<const uint2*>(lBbuf + r * TPAD + c * 8);
                *reinterpret_cast<uint2*>(reinterpret_cast<unsigned char*>(h)
                                          + (size_t)(rowBase + r) * 256 + c * 8) = v;
            }
        }
    }
}

// ---------------------------------------------------------------------------
// Pull: one 512-thread block per half-bucket region — owns all its records
// (no filtering). Counting sort (64 bins), then 2-slot x 8-edge DMA ring
// (vmcnt(2)), segment-hoisted unroll-2 consume with fma_mix. Fused GELU.
// ---------------------------------------------------------------------------
__global__ __launch_bounds__(512) void pull_kernel(const unsigned short* __restrict__ h,
                                                   const int* __restrict__ bucketCursor,
                                                   const uint2* __restrict__ ebuf,
                                                   float* __restrict__ out) {
    __shared__ uint2 srec[CAP];                              // 10240 B
    __shared__ int cnt[64];
    __shared__ int start[65];
    __shared__ int cur[64];
    __shared__ __align__(16) unsigned char hbuf[8 * 4096];   // 32 KB

    const int t = threadIdx.x;
    const int lane = t & 63;
    const int w = t >> 6;                // 8 waves
    const int hb = blockIdx.x;           // half-bucket id
    const int nodeBase = hb * 64;

    unsigned char* hbufW = hbuf + w * 4096;

    float2 acc[8];
#pragma unroll
    for (int i = 0; i < 8; ++i) acc[i] = (float2){0.f, 0.f};

    const int n = min(bucketCursor[hb * CURSTRIDE], CAPB);
    const uint2* eb = ebuf + (size_t)hb * CAPB;

    if (t < 64) cnt[t] = 0;
    __syncthreads();

    // pass 1: read records once into registers; histogram local dst
    uint2 rcache[3];
#pragma unroll
    for (int it = 0; it < 3; ++it) {
        int j = t + 512 * it;
        uint2 r = (j < n) ? eb[j] : (uint2){0xFFFFFFFFu, 0u};
        rcache[it] = r;
        if (j < n) atomicAdd(&cnt[(r.x >> 17) & 63], 1);
    }
    __syncthreads();

    if (w == 0) {
        int c = cnt[lane];
        int s = c;
        for (int off = 1; off < 64; off <<= 1) {
            int v = __shfl_up(s, off);
            if (lane >= off) s += v;
        }
        start[lane] = s - c;
        cur[lane] = s - c;
        if (lane == 63) start[64] = s;
    }
    __syncthreads();

    // pass 2: scatter cached records into srec sorted by local dst
#pragma unroll
    for (int it = 0; it < 3; ++it) {
        int j = t + 512 * it;
        if (j < n) {
            uint2 rec = rcache[it];
            int p = atomicAdd(&cur[(rec.x >> 17) & 63], 1);
            srec[p] = rec;
        }
    }
    __syncthreads();

    // ---- streamed accumulate: wave w owns nodes [w*8, w*8+8) ----
    const int wbeg = start[w * 8];
    const int wend = start[w * 8 + 8];
    int issued = 0;
    int consumed = 0;

    auto issue_group = [&]() {
        int gbase = wbeg + issued * 8;
#pragma unroll
        for (int q = 0; q < 2; ++q) {
            int idx = min(gbase + q * 4 + (lane >> 4), wend - 1);
            unsigned int rx = reinterpret_cast<const unsigned int*>(&srec[idx])[0];
            const unsigned char* gp = reinterpret_cast<const unsigned char*>(h)
                                      + (size_t)(rx & 0x1FFFFu) * 256 + (size_t)((lane & 15) * 16);
            unsigned char* lp = hbufW + (issued & 1) * 2048 + q * 1024;
            __builtin_amdgcn_global_load_lds((ASG const unsigned int*)(const void*)gp,
                                             (ASL unsigned int*)(void*)lp, 16, 0, 0);
        }
        issued++;
    };

    if (wend > wbeg) { issue_group(); issue_group(); }

    int gate = wbeg;
    const unsigned char* slotcur = hbufW;
    const unsigned int* srec_dw = reinterpret_cast<const unsigned int*>(srec);

#pragma unroll
    for (int i = 0; i < 8; ++i) {
        const int s1 = start[w * 8 + i + 1];
        int e = start[w * 8 + i];
        float2 a = acc[i];
        while (e < s1) {
            if (e >= gate) {
                if (consumed) issue_group();
                asm volatile("s_waitcnt vmcnt(2)" ::: "memory");
                __builtin_amdgcn_sched_barrier(0);
                slotcur = hbufW + (consumed & 1) * 2048;
                consumed++;
                gate += 8;
            }
            const int lim = min(s1, gate);
            const unsigned char* hp = slotcur + ((e - wbeg) & 7) * 256 + lane * 4;
            for (; e + 1 < lim; e += 2) {
                unsigned int h0 = *reinterpret_cast<const unsigned int*>(hp);
                unsigned int h1 = *reinterpret_cast<const unsigned int*>(hp + 256);
                float v0 = __uint_as_float(srec_dw[e * 2 + 1]);
                float v1 = __uint_as_float(srec_dw[e * 2 + 3]);
                fma_f16lo(a.x, h0, v0);
                fma_f16hi(a.y, h0, v0);
                fma_f16lo(a.x, h1, v1);
                fma_f16hi(a.y, h1, v1);
                hp += 512;
            }
            if (e < lim) {
                unsigned int h0 = *reinterpret_cast<const unsigned int*>(hp);
                float v0 = __uint_as_float(srec_dw[e * 2 + 1]);
                fma_f16lo(a.x, h0, v0);
                fma_f16hi(a.y, h0, v0);
                ++e;
            }
        }
        acc[i] = a;
    }
    __syncthreads();   // drains dangling DMA

    // epilogue: exact GELU + coalesced write
    const float is2 = 0.70710678118654752f;
#pragma unroll
    for (int i = 0; i < 8; ++i) {
        int node = nodeBase + w * 8 + i;
        if (node < NN) {
            float a0 = acc[i].x, a1 = acc[i].y;
            a0 = 0.5f * a0 * (1.f + erff(a0 * is2));
            a1 = 0.5f * a1 * (1.f + erff(a1 * is2));
            float2 o; o.x = a0; o.y = a1;
            *reinterpret_cast<float2*>(out + (size_t)node * D + lane * 2) = o;
        }
    }
}

extern "C" void kernel_launch(void* const* d_in, const int* in_sizes, int n_in,
                              void* d_out, int out_size, void* d_ws, size_t ws_size,
                              hipStream_t stream) {
    const float* x    = (const float*)d_in[0];
    const float* W    = (const float*)d_in[1];
    const float* vals = (const float*)d_in[2];
    const int*   src  = (const int*)d_in[3];
    const int*   dst  = (const int*)d_in[4];
    float* out = (float*)d_out;

    char* ws = (char*)d_ws;
    size_t off = 0;
    unsigned short* h    = (unsigned short*)(ws + off); off += (size_t)NN * D * 2;
    int* bucketCursor    = (int*)(ws + off);            off += (size_t)NHB * CURSTRIDE * 4;
    off = (off + 15) & ~(size_t)15;
    unsigned short* Wswz = (unsigned short*)(ws + off); off += (size_t)D * D * 2;
    off = (off + 15) & ~(size_t)15;
    uint2* ebuf          = (uint2*)(ws + off);          off += (size_t)NHB * CAPB * 8;

    wconv_kernel<<<8, 256, 0, stream>>>(W, Wswz, bucketCursor);
    gemm_scatter_kernel<<<GRID, 256, 0, stream>>>(
        x, Wswz, h, src, dst, vals, bucketCursor, ebuf);
    pull_kernel<<<NHB, 512, 0, stream>>>(h, bucketCursor, ebuf, out);
}

// Round 23
// 118.979 us; speedup vs baseline: 1.3260x; 1.3260x over previous
//
#include <hip/hip_runtime.h>
#include <math.h>

#define NN 100000
#define NE 1600000
#define D 128

#define NB 782                          // buckets of 128 dst-nodes
#define CAPB 2560                       // fixed ebuf capacity per bucket
#define CURSTRIDE 16                    // cursor padded to one 64B line per bucket
#define SC_BLOCKS 512                   // scatter role blocks
#define SC_CHUNK 3125                   // 512 x 3125 = 1.6M exactly
#define SC_IT 13                        // ceil(3125/256)
#define CAP 1408                        // pull sorted tile (half-bucket, mean 1023, +12 sigma)

#define BM 64                           // rows per gemm block
#define GM_BLOCKS 1563                  // ceil(NN/64)
#define GRID (SC_BLOCKS + GM_BLOCKS)    // 2075
#define TPAD 264                        // transpose-epilogue row stride (bytes)
#define PULL_GRID 1568                  // 98 groups x 16 (pair-XCD swizzle, tail-guarded)

#define ASG __attribute__((address_space(1)))
#define ASL __attribute__((address_space(3)))

typedef __attribute__((ext_vector_type(8))) short bf16x8;
typedef __attribute__((ext_vector_type(4))) float f32x4;
typedef __attribute__((ext_vector_type(4))) unsigned int u32x4;

__device__ __forceinline__ unsigned int cvt_pk_bf16(float lo, float hi) {
    unsigned int r;
    asm("v_cvt_pk_bf16_f32 %0, %1, %2" : "=v"(r) : "v"(lo), "v"(hi));
    return r;
}

// Pack two f32 -> packed f16 pair (round toward zero), as a dword.
__device__ __forceinline__ unsigned int cvt_pk_f16(float lo, float hi) {
    auto p = __builtin_amdgcn_cvt_pkrtz(lo, hi);
    return __builtin_bit_cast(unsigned int, p);
}

// Single-instruction f16-half * f32 + f32 (VOP3P v_fma_mix_f32, gfx9+).
__device__ __forceinline__ void fma_f16lo(float& acc, unsigned int h, float v) {
    asm("v_fma_mix_f32 %0, %1, %2, %0 op_sel:[0,0,0] op_sel_hi:[1,0,0]"
        : "+v"(acc) : "v"(h), "v"(v));
}
__device__ __forceinline__ void fma_f16hi(float& acc, unsigned int h, float v) {
    asm("v_fma_mix_f32 %0, %1, %2, %0 op_sel:[1,0,0] op_sel_hi:[1,0,0]"
        : "+v"(acc) : "v"(h), "v"(v));
}

// ---------------------------------------------------------------------------
// W precompute (fp32 -> bf16, slot-swizzled) + padded bucketCursor zeroing.
// ---------------------------------------------------------------------------
__global__ __launch_bounds__(256) void wconv_kernel(const float* __restrict__ W,
                                                    unsigned short* __restrict__ Wswz,
                                                    int* __restrict__ bucketCursor) {
    int i = blockIdx.x * 256 + threadIdx.x;   // 2048 threads total
    int r = i >> 4, s = i & 15;
    const float4* wp = reinterpret_cast<const float4*>(W + (size_t)r * D + s * 8);
    float4 v0 = wp[0], v1 = wp[1];
    uint2 a, b;
    a.x = cvt_pk_bf16(v0.x, v0.y); a.y = cvt_pk_bf16(v0.z, v0.w);
    b.x = cvt_pk_bf16(v1.x, v1.y); b.y = cvt_pk_bf16(v1.z, v1.w);
    int so = s ^ (r & 15);
    unsigned short* op = Wswz + (size_t)r * D + so * 8;
    *reinterpret_cast<uint2*>(op)     = a;
    *reinterpret_cast<uint2*>(op + 4) = b;
    for (int z = i; z < NB * CURSTRIDE; z += 2048) bucketCursor[z] = 0;
}

// ---------------------------------------------------------------------------
// FUSED gemm + scatter (r21-identical: 782 buckets, padded cursors,
// BM=64 reg-A gemm, f16 h epilogue).
// ---------------------------------------------------------------------------
__global__ __launch_bounds__(256) void gemm_scatter_kernel(const float* __restrict__ x,
                                                           const unsigned short* __restrict__ Wswz,
                                                           unsigned short* __restrict__ h,
                                                           const int* __restrict__ src,
                                                           const int* __restrict__ dst,
                                                           const float* __restrict__ vals,
                                                           int* __restrict__ bucketCursor,
                                                           uint2* __restrict__ ebuf) {
    __shared__ __align__(16) unsigned char smem[40960];
    const int tid = threadIdx.x;
    const int lane = tid & 63;
    const int w = tid >> 6;
    const int g = blockIdx.x;

    if (g < SC_BLOCKS) {
        // ================= SCATTER role =================
        uint2* s_rec        = reinterpret_cast<uint2*>(smem);                    // 25000 B
        int*   l_off        = reinterpret_cast<int*>(smem + 25000);              // 3128 B
        int*   l_cur        = reinterpret_cast<int*>(smem + 28128);              // 3128 B
        int*   l_cnt        = reinterpret_cast<int*>(smem + 31256);              // 3128 B
        int*   wtot         = reinterpret_cast<int*>(smem + 34384);              // 16 B
        unsigned short* s_b = reinterpret_cast<unsigned short*>(smem + 34400);   // 6250 B

        const int t = tid;
        const int cb = g * SC_CHUNK;

        for (int i = t; i < NB; i += 256) l_cnt[i] = 0;
        __syncthreads();

        int dreg[SC_IT];
#pragma unroll
        for (int i = 0; i < SC_IT; ++i) {
            int o = t + 256 * i;
            dreg[i] = (o < SC_CHUNK) ? dst[cb + o] : -1;
            if (dreg[i] >= 0) atomicAdd(&l_cnt[dreg[i] >> 7], 1);
        }
        __syncthreads();

        int c[4];
        int s = 0;
#pragma unroll
        for (int i = 0; i < 4; ++i) {
            int b = 4 * t + i;
            c[i] = (b < NB) ? l_cnt[b] : 0;
            s += c[i];
        }
        int incl = s;
#pragma unroll
        for (int off = 1; off < 64; off <<= 1) {
            int v = __shfl_up(incl, off);
            if (lane >= off) incl += v;
        }
        if (lane == 63) wtot[w] = incl;
        __syncthreads();
        int run = incl - s;
        for (int k = 0; k < 4; ++k) if (k < w) run += wtot[k];
#pragma unroll
        for (int i = 0; i < 4; ++i) {
            int b = 4 * t + i;
            if (b < NB) {
                l_cur[b] = run;
                int gbase = b * CAPB +
                    (c[i] ? atomicAdd(&bucketCursor[b * CURSTRIDE], c[i]) : 0);
                l_off[b] = gbase - run;
            }
            run += c[i];
        }
        __syncthreads();

#pragma unroll
        for (int i = 0; i < SC_IT; ++i) {
            int o = t + 256 * i;
            if (dreg[i] >= 0) {
                int dn = dreg[i];
                int b = dn >> 7;
                uint2 rec;
                rec.x = (unsigned int)src[cb + o] | ((unsigned int)(dn & 127) << 17);
                rec.y = __float_as_uint(vals[cb + o]);
                int lofs = atomicAdd(&l_cur[b], 1);
                s_rec[lofs] = rec;
                s_b[lofs] = (unsigned short)b;
            }
        }
        __syncthreads();

#pragma unroll
        for (int i = 0; i < SC_IT; ++i) {
            int j = t + 256 * i;
            if (j < SC_CHUNK) {
                int b = s_b[j];
                ebuf[l_off[b] + j] = s_rec[j];
            }
        }
    } else {
        // ================= GEMM role (BM=64, reg-A) =================
        unsigned char* lBbuf = smem;                                   // 32768 B
        const int rowBase = (g - SC_BLOCKS) * BM;

#pragma unroll
        for (int q = 0; q < 8; ++q) {
            const unsigned char* gp = reinterpret_cast<const unsigned char*>(Wswz)
                                      + (size_t)((w * 8 + q) * 1024 + lane * 16);
            unsigned char* lp = lBbuf + (w * 8 + q) * 1024;
            __builtin_amdgcn_global_load_lds((ASG const unsigned int*)(const void*)gp,
                                             (ASL unsigned int*)(void*)lp, 16, 0, 0);
        }

        const int l16 = lane & 15;
        const int arow = min(rowBase + w * 16 + l16, NN - 1);
        const float* xrow = x + (size_t)arow * D + (lane >> 4) * 8;

        bf16x8 afr[4];
#pragma unroll
        for (int kk = 0; kk < 4; ++kk) {
            float4 v0 = *reinterpret_cast<const float4*>(xrow + kk * 32);
            float4 v1 = *reinterpret_cast<const float4*>(xrow + kk * 32 + 4);
            u32x4 u;
            u[0] = cvt_pk_bf16(v0.x, v0.y);
            u[1] = cvt_pk_bf16(v0.z, v0.w);
            u[2] = cvt_pk_bf16(v1.x, v1.y);
            u[3] = cvt_pk_bf16(v1.z, v1.w);
            afr[kk] = __builtin_bit_cast(bf16x8, u);
        }
        __syncthreads();   // drains vmcnt (W DMA)

        const int kx16 = (lane >> 4) * 16;
        f32x4 acc[8];
#pragma unroll
        for (int j = 0; j < 8; ++j) acc[j] = (f32x4){0.f, 0.f, 0.f, 0.f};

        const int bxor = l16 << 4;
#pragma unroll
        for (int kk = 0; kk < 4; ++kk) {
            int kbyte = kk * 64 + kx16;
#pragma unroll
            for (int j = 0; j < 8; ++j) {
                int row = j * 16 + l16;
                bf16x8 b = *reinterpret_cast<const bf16x8*>(
                    lBbuf + row * 256 + (kbyte ^ bxor));
                acc[j] = __builtin_amdgcn_mfma_f32_16x16x32_bf16(afr[kk], b, acc[j], 0, 0, 0);
            }
        }
        __syncthreads();   // all waves done with lB -> reuse as transpose buffer

        // Transpose epilogue (h packed f16): layout/stores unchanged.
        const int lr0 = w * 16 + (lane >> 4) * 4;
#pragma unroll
        for (int j = 0; j < 8; ++j) {
            int col = j * 16 + l16;
            unsigned int d01 = cvt_pk_f16(acc[j][0], acc[j][1]);
            unsigned int d23 = cvt_pk_f16(acc[j][2], acc[j][3]);
            unsigned char* p0 = lBbuf + lr0 * TPAD + col * 2;
            *reinterpret_cast<unsigned short*>(p0)            = (unsigned short)d01;
            *reinterpret_cast<unsigned short*>(p0 + TPAD)     = (unsigned short)(d01 >> 16);
            *reinterpret_cast<unsigned short*>(p0 + 2 * TPAD) = (unsigned short)d23;
            *reinterpret_cast<unsigned short*>(p0 + 3 * TPAD) = (unsigned short)(d23 >> 16);
        }
        __syncthreads();

#pragma unroll
        for (int i = 0; i < 8; ++i) {
            int f = tid + 256 * i;
            int r = f >> 5, c = f & 31;
            if (rowBase + r < NN) {
                uint2 v = *reinterpret_cast<const uint2*>(lBbuf + r * TPAD + c * 8);
                *reinterpret_cast<uint2*>(reinterpret_cast<unsigned char*>(h)
                                          + (size_t)(rowBase + r) * 256 + c * 8) = v;
            }
        }
    }
}

// ---------------------------------------------------------------------------
// Pull (r21 shape + pair-XCD swizzle): blocks (p, p+8) handle the two halves
// of one bucket -> same XCD -> shared-L2 ebuf region (second read hits L2).
// Counting sort, 2-slot x 8-edge DMA ring (vmcnt(2)), segment-hoisted
// unroll-2 fma_mix consume, fused exact GELU.
// ---------------------------------------------------------------------------
__global__ __launch_bounds__(512) void pull_kernel(const unsigned short* __restrict__ h,
                                                   const int* __restrict__ bucketCursor,
                                                   const uint2* __restrict__ ebuf,
                                                   float* __restrict__ out) {
    __shared__ uint2 srec[CAP];                              // 11264 B
    __shared__ int cnt[64];
    __shared__ int start[65];
    __shared__ int cur[64];
    __shared__ __align__(16) unsigned char hbuf[8 * 4096];   // 32 KB

    const int t = threadIdx.x;
    const int lane = t & 63;
    const int w = t >> 6;                // 8 waves
    const int p = blockIdx.x;
    const int b = (p >> 4) * 8 + (p & 7);
    const int half = (p >> 3) & 1;
    if (b >= NB) return;
    const int nodeBase = b * 128 + half * 64;

    unsigned char* hbufW = hbuf + w * 4096;

    float2 acc[8];
#pragma unroll
    for (int i = 0; i < 8; ++i) acc[i] = (float2){0.f, 0.f};

    const int n = min(bucketCursor[b * CURSTRIDE], CAPB);
    const uint2* eb = ebuf + (size_t)b * CAPB;

    if (t < 64) cnt[t] = 0;
    __syncthreads();

    // pass 1: read records once into registers; histogram own-half dst
    uint2 rcache[5];
#pragma unroll
    for (int it = 0; it < 5; ++it) {
        int j = t + 512 * it;
        uint2 r = (j < n) ? eb[j] : (uint2){0xFFFFFFFFu, 0u};
        rcache[it] = r;
        if (j < n) {
            int dl = (int)((r.x >> 17) & 127);
            if ((dl >> 6) == half) atomicAdd(&cnt[dl & 63], 1);
        }
    }
    __syncthreads();

    if (w == 0) {
        int c = cnt[lane];
        int s = c;
        for (int off = 1; off < 64; off <<= 1) {
            int v = __shfl_up(s, off);
            if (lane >= off) s += v;
        }
        start[lane] = s - c;
        cur[lane] = s - c;
        if (lane == 63) start[64] = s;
    }
    __syncthreads();

    // pass 2: scatter own cached records into srec sorted by local dst
#pragma unroll
    for (int it = 0; it < 5; ++it) {
        int j = t + 512 * it;
        if (j < n) {
            uint2 rec = rcache[it];
            int dl = (int)((rec.x >> 17) & 127);
            if ((dl >> 6) == half) {
                int pidx = atomicAdd(&cur[dl & 63], 1);
                srec[pidx] = rec;
            }
        }
    }
    __syncthreads();

    // ---- streamed accumulate: wave w owns nodes [w*8, w*8+8) ----
    const int wbeg = start[w * 8];
    const int wend = start[w * 8 + 8];
    int issued = 0;
    int consumed = 0;

    auto issue_group = [&]() {
        int gbase = wbeg + issued * 8;
#pragma unroll
        for (int q = 0; q < 2; ++q) {
            int idx = min(gbase + q * 4 + (lane >> 4), wend - 1);
            unsigned int rx = reinterpret_cast<const unsigned int*>(&srec[idx])[0];
            const unsigned char* gp = reinterpret_cast<const unsigned char*>(h)
                                      + (size_t)(rx & 0x1FFFFu) * 256 + (size_t)((lane & 15) * 16);
            unsigned char* lp = hbufW + (issued & 1) * 2048 + q * 1024;
            __builtin_amdgcn_global_load_lds((ASG const unsigned int*)(const void*)gp,
                                             (ASL unsigned int*)(void*)lp, 16, 0, 0);
        }
        issued++;
    };

    if (wend > wbeg) { issue_group(); issue_group(); }

    int gate = wbeg;
    const unsigned char* slotcur = hbufW;
    const unsigned int* srec_dw = reinterpret_cast<const unsigned int*>(srec);

#pragma unroll
    for (int i = 0; i < 8; ++i) {
        const int s1 = start[w * 8 + i + 1];
        int e = start[w * 8 + i];
        float2 a = acc[i];
        while (e < s1) {
            if (e >= gate) {
                if (consumed) issue_group();
                asm volatile("s_waitcnt vmcnt(2)" ::: "memory");
                __builtin_amdgcn_sched_barrier(0);
                slotcur = hbufW + (consumed & 1) * 2048;
                consumed++;
                gate += 8;
            }
            const int lim = min(s1, gate);
            const unsigned char* hp = slotcur + ((e - wbeg) & 7) * 256 + lane * 4;
            for (; e + 1 < lim; e += 2) {
                unsigned int h0 = *reinterpret_cast<const unsigned int*>(hp);
                unsigned int h1 = *reinterpret_cast<const unsigned int*>(hp + 256);
                float v0 = __uint_as_float(srec_dw[e * 2 + 1]);
                float v1 = __uint_as_float(srec_dw[e * 2 + 3]);
                fma_f16lo(a.x, h0, v0);
                fma_f16hi(a.y, h0, v0);
                fma_f16lo(a.x, h1, v1);
                fma_f16hi(a.y, h1, v1);
                hp += 512;
            }
            if (e < lim) {
                unsigned int h0 = *reinterpret_cast<const unsigned int*>(hp);
                float v0 = __uint_as_float(srec_dw[e * 2 + 1]);
                fma_f16lo(a.x, h0, v0);
                fma_f16hi(a.y, h0, v0);
                ++e;
            }
        }
        acc[i] = a;
    }
    __syncthreads();   // drains dangling DMA

    // epilogue: exact GELU + coalesced write
    const float is2 = 0.70710678118654752f;
#pragma unroll
    for (int i = 0; i < 8; ++i) {
        int node = nodeBase + w * 8 + i;
        if (node < NN) {
            float a0 = acc[i].x, a1 = acc[i].y;
            a0 = 0.5f * a0 * (1.f + erff(a0 * is2));
            a1 = 0.5f * a1 * (1.f + erff(a1 * is2));
            float2 o; o.x = a0; o.y = a1;
            *reinterpret_cast<float2*>(out + (size_t)node * D + lane * 2) = o;
        }
    }
}

extern "C" void kernel_launch(void* const* d_in, const int* in_sizes, int n_in,
                              void* d_out, int out_size, void* d_ws, size_t ws_size,
                              hipStream_t stream) {
    const float* x    = (const float*)d_in[0];
    const float* W    = (const float*)d_in[1];
    const float* vals = (const float*)d_in[2];
    const int*   src  = (const int*)d_in[3];
    const int*   dst  = (const int*)d_in[4];
    float* out = (float*)d_out;

    char* ws = (char*)d_ws;
    size_t off = 0;
    unsigned short* h    = (unsigned short*)(ws + off); off += (size_t)NN * D * 2;
    int* bucketCursor    = (int*)(ws + off);            off += (size_t)NB * CURSTRIDE * 4;
    off = (off + 15) & ~(size_t)15;
    unsigned short* Wswz = (unsigned short*)(ws + off); off += (size_t)D * D * 2;
    off = (off + 15) & ~(size_t)15;
    uint2* ebuf          = (uint2*)(ws + off);          off += (size_t)NB * CAPB * 8;

    wconv_kernel<<<8, 256, 0, stream>>>(W, Wswz, bucketCursor);
    gemm_scatter_kernel<<<GRID, 256, 0, stream>>>(
        x, Wswz, h, src, dst, vals, bucketCursor, ebuf);
    pull_kernel<<<PULL_GRID, 512, 0, stream>>>(h, bucketCursor, ebuf, out);
}